// Round 2
// baseline (2545.852 us; speedup 1.0000x reference)
//
#include <hip/hip_runtime.h>
#include <hip/hip_bf16.h>

// GRNNTransformGated: 13-level binary-tree gated RNN.
// Level sizes n_j = 64*2^j, j=0..12; total rows 524224, H=64, F=7.
// Round 1: inputs/outputs are FLOAT32 (NaN in round 0 was f32-read-as-bf16).
//   kernel A: u = relu(contents @ W_u^T + b_u) for ALL rows -> ws (bf16)
//   kernel B (per interior level, 12 launches): block = 192 threads, 16 rows.
//     Stage hhu=[h_L,h_R,u] (f32) in LDS; thread o owns one output column and
//     streams its weight row ONCE per block (weights reused across 16 rows via
//     LDS broadcast) -> weight traffic ~450KB/block, L2-resident.
// ws layout (bf16): u_all (67.1MB) | buf_odd (16.8MB) | buf_even (8.4MB)

#define H 64
#define F 7
#define TILE 16

__device__ __forceinline__ float bf2f(__hip_bfloat16 x) { return __bfloat162float(x); }

__global__ void u_kernel(const float* __restrict__ contents,
                         const float* __restrict__ W_u,
                         const float* __restrict__ b_u,
                         __hip_bfloat16* __restrict__ u_all, int total) {
    int idx = blockIdx.x * blockDim.x + threadIdx.x;
    if (idx >= total) return;
    int row = idx >> 6, h = idx & 63;
    const float* c = contents + (size_t)row * F;
    const float* w = W_u + (size_t)h * F;
    float acc = b_u[h];
#pragma unroll
    for (int k = 0; k < F; ++k) acc += c[k] * w[k];
    u_all[idx] = __float2bfloat16(fmaxf(acc, 0.f));
}

__global__ __launch_bounds__(192) void level_kernel(
    const __hip_bfloat16* __restrict__ u_lvl,     // n x H (bf16)
    const __hip_bfloat16* __restrict__ up_prev,   // 2n x H (bf16)
    const float* __restrict__ W_r, const float* __restrict__ b_r,
    const float* __restrict__ W_h, const float* __restrict__ b_h,
    const float* __restrict__ W_z, const float* __restrict__ b_z,
    __hip_bfloat16* __restrict__ up_cur,          // n x H (bf16)
    float* __restrict__ out)                      // 4096 (f32) or nullptr
{
    __shared__ __align__(16) float s_hhu[TILE][200];  // 192 + pad
    __shared__ __align__(16) float s_t[TILE][200];    // r * hhu
    __shared__ __align__(16) float s_hH[TILE][72];    // 64 + pad
    __shared__ __align__(16) float s_z[TILE][260];    // 256 + pad

    const int tid = threadIdx.x;      // 0..191
    const int r0 = blockIdx.x * TILE;

    // ---- stage hhu = [h_L, h_R, u] as f32 ----
#pragma unroll
    for (int t = 0; t < TILE; ++t) {
        int row = r0 + t;
        float v;
        if (tid < 64)        v = bf2f(up_prev[(size_t)(2 * row) * H + tid]);
        else if (tid < 128)  v = bf2f(up_prev[(size_t)(2 * row + 1) * H + (tid - 64)]);
        else                 v = bf2f(u_lvl[(size_t)row * H + (tid - 128)]);
        s_hhu[t][tid] = v;
    }
    __syncthreads();

    // ---- r = sigmoid(hhu @ W_r^T + b_r); s_t = r * hhu ----  (o = tid, 192 outputs)
    {
        const int o = tid;
        float acc[TILE];
#pragma unroll
        for (int t = 0; t < TILE; ++t) acc[t] = 0.f;
        const float4* w4 = (const float4*)(W_r + (size_t)o * 192);
        for (int kc = 0; kc < 48; ++kc) {           // 4 k per chunk
            float4 w = w4[kc];
#pragma unroll
            for (int t = 0; t < TILE; ++t) {
                const float4 a = *(const float4*)&s_hhu[t][kc * 4];
                acc[t] += a.x * w.x + a.y * w.y + a.z * w.z + a.w * w.w;
            }
        }
        float bb = b_r[o];
#pragma unroll
        for (int t = 0; t < TILE; ++t) {
            float rr = 1.f / (1.f + __expf(-(acc[t] + bb)));
            s_t[t][o] = rr * s_hhu[t][o];
        }
    }
    __syncthreads();

    // ---- h_H = relu((r*hhu) @ W_h^T + b_h) ----  (o = tid < 64)
    if (tid < 64) {
        const int o = tid;
        float acc[TILE];
#pragma unroll
        for (int t = 0; t < TILE; ++t) acc[t] = 0.f;
        const float4* w4 = (const float4*)(W_h + (size_t)o * 192);
        for (int kc = 0; kc < 48; ++kc) {
            float4 w = w4[kc];
#pragma unroll
            for (int t = 0; t < TILE; ++t) {
                const float4 a = *(const float4*)&s_t[t][kc * 4];
                acc[t] += a.x * w.x + a.y * w.y + a.z * w.z + a.w * w.w;
            }
        }
        float bb = b_h[o];
#pragma unroll
        for (int t = 0; t < TILE; ++t) s_hH[t][o] = fmaxf(acc[t] + bb, 0.f);
    }
    __syncthreads();

    // ---- z = [h_H, hhu] @ W_z^T + b_z ----  (256 outputs: o=tid, then o=tid+192)
    for (int pass = 0; pass < 2; ++pass) {
        const int o = tid + pass * 192;
        if (o < 256) {
            float acc[TILE];
#pragma unroll
            for (int t = 0; t < TILE; ++t) acc[t] = 0.f;
            const float4* w4 = (const float4*)(W_z + (size_t)o * 256);
            for (int kc = 0; kc < 16; ++kc) {       // k 0..63 -> h_H
                float4 w = w4[kc];
#pragma unroll
                for (int t = 0; t < TILE; ++t) {
                    const float4 a = *(const float4*)&s_hH[t][kc * 4];
                    acc[t] += a.x * w.x + a.y * w.y + a.z * w.z + a.w * w.w;
                }
            }
            for (int kc = 0; kc < 48; ++kc) {       // k 64..255 -> hhu
                float4 w = w4[16 + kc];
#pragma unroll
                for (int t = 0; t < TILE; ++t) {
                    const float4 a = *(const float4*)&s_hhu[t][kc * 4];
                    acc[t] += a.x * w.x + a.y * w.y + a.z * w.z + a.w * w.w;
                }
            }
            float bb = b_z[o];
#pragma unroll
            for (int t = 0; t < TILE; ++t) s_z[t][o] = acc[t] + bb;
        }
    }
    __syncthreads();

    // ---- softmax over 4 groups + gated blend ----
    for (int i = tid; i < TILE * H; i += 192) {
        int t = i >> 6, h = i & 63;
        float z0 = s_z[t][h], z1 = s_z[t][64 + h], z2 = s_z[t][128 + h], z3 = s_z[t][192 + h];
        float m = fmaxf(fmaxf(z0, z1), fmaxf(z2, z3));
        float e0 = __expf(z0 - m), e1 = __expf(z1 - m), e2 = __expf(z2 - m), e3 = __expf(z3 - m);
        float inv = 1.f / (e0 + e1 + e2 + e3);
        float v = (e0 * s_hH[t][h] + e1 * s_hhu[t][h] + e2 * s_hhu[t][64 + h] +
                   e3 * s_hhu[t][128 + h]) * inv;
        int row = r0 + t;
        up_cur[(size_t)row * H + h] = __float2bfloat16(v);
        if (out) out[(size_t)row * H + h] = v;
    }
}

extern "C" void kernel_launch(void* const* d_in, const int* in_sizes, int n_in,
                              void* d_out, int out_size, void* d_ws, size_t ws_size,
                              hipStream_t stream) {
    const float* contents = (const float*)d_in[0];
    const float* W_u = (const float*)d_in[1];
    const float* b_u = (const float*)d_in[2];
    const float* W_r = (const float*)d_in[3];
    const float* b_r = (const float*)d_in[4];
    const float* W_h = (const float*)d_in[5];
    const float* b_h = (const float*)d_in[6];
    const float* W_z = (const float*)d_in[7];
    const float* b_z = (const float*)d_in[8];
    float* out = (float*)d_out;

    // tree geometry
    int SIZES[13], OFFS[14];
    OFFS[0] = 0;
    for (int j = 0; j < 13; ++j) { SIZES[j] = 64 << j; OFFS[j + 1] = OFFS[j] + SIZES[j]; }
    const int n_total = OFFS[13];  // 524224

    // workspace layout (all bf16): u_all | buf_odd | buf_even
    char* ws = (char*)d_ws;
    __hip_bfloat16* u_all = (__hip_bfloat16*)ws;
    size_t U_BYTES = (size_t)n_total * H * sizeof(__hip_bfloat16);          // 67,100,672
    __hip_bfloat16* buf_odd = (__hip_bfloat16*)(ws + U_BYTES);              // 131072*64
    __hip_bfloat16* buf_even = (__hip_bfloat16*)(ws + U_BYTES + (size_t)131072 * H * 2);

    // kernel A: u for all rows
    int totalA = n_total * H;
    u_kernel<<<(totalA + 255) / 256, 256, 0, stream>>>(contents, W_u, b_u, u_all, totalA);

    // levels 11..0 (level 12's up == its u, read straight out of u_all)
    const __hip_bfloat16* up_prev = u_all + (size_t)OFFS[12] * H;
    for (int j = 11; j >= 0; --j) {
        int n = SIZES[j];
        __hip_bfloat16* up_cur = (j & 1) ? buf_odd : buf_even;
        const __hip_bfloat16* u_lvl = u_all + (size_t)OFFS[j] * H;
        level_kernel<<<n / TILE, 192, 0, stream>>>(
            u_lvl, up_prev, W_r, b_r, W_h, b_h, W_z, b_z,
            up_cur, (j == 0) ? out : nullptr);
        up_prev = up_cur;
    }
}

// Round 3
// 752.833 us; speedup vs baseline: 3.3817x; 3.3817x over previous
//
#include <hip/hip_runtime.h>
#include <hip/hip_bf16.h>

// GRNNTransformGated, round 2: MFMA (16x16x32 bf16) rewrite.
// Per interior level: block = 256 thr (4 waves) x 64 rows. Wave w owns rows
// 16w..16w+15 (M-slice) and computes ALL N columns; A-frags in registers,
// B-frags (bf16 weights, pre-converted) streamed from L2.
// mm1: hhu(64x192) @ W_r^T -> r -> t = sigmoid*hhu   (N=192, K=192)
// mm2: t @ W_h^T -> h_H relu                         (N=64,  K=192)
// mm3: [h_H,hhu] @ W_z^T -> z; softmax-4 gate        (N=256, K=256)
// mm3 N-tiles grouped {16c,+64,+128,+192} so each lane holds all 4 z-group
// values for its (row,col) -> softmax + gating in registers.
// u = relu(contents@W_u^T) computed in-kernel (F=7, trivial); only level-12 u
// is materialized. ws: u12 33.5MB | buf_odd 16.8MB | buf_even 8.4MB | wbf16.

#define H 64
#define F 7

typedef __bf16 bf16x8 __attribute__((ext_vector_type(8)));
typedef float f32x4 __attribute__((ext_vector_type(4)));
typedef unsigned short bfr;   // raw bf16 bits

__device__ __forceinline__ float bfr2f(bfr v) { return __uint_as_float(((unsigned)v) << 16); }
__device__ __forceinline__ bfr f2bfr(float f) {
    __hip_bfloat16 h = __float2bfloat16(f);
    return __builtin_bit_cast(bfr, h);
}

__global__ void convert_weights(const float* __restrict__ Wr, const float* __restrict__ Wh,
                                const float* __restrict__ Wz,
                                bfr* __restrict__ wr, bfr* __restrict__ wh, bfr* __restrict__ wz) {
    int i = blockIdx.x * 256 + threadIdx.x;   // grid covers 65536
    if (i < 36864) wr[i] = f2bfr(Wr[i]);
    if (i < 12288) wh[i] = f2bfr(Wh[i]);
    if (i < 65536) wz[i] = f2bfr(Wz[i]);
}

__global__ void u12_kernel(const float* __restrict__ contents12,
                           const float* __restrict__ W_u, const float* __restrict__ b_u,
                           bfr* __restrict__ u12, int total) {
    int idx = blockIdx.x * blockDim.x + threadIdx.x;
    if (idx >= total) return;
    int row = idx >> 6, h = idx & 63;
    const float* c = contents12 + (size_t)row * F;
    const float* w = W_u + (size_t)h * F;
    float acc = b_u[h];
#pragma unroll
    for (int k = 0; k < F; ++k) acc += c[k] * w[k];
    u12[idx] = f2bfr(fmaxf(acc, 0.f));
}

__global__ __launch_bounds__(256) void level_kernel(
    const float* __restrict__ contents_lvl,   // level rows x 7 (f32)
    const float* __restrict__ W_u, const float* __restrict__ b_u,
    const bfr* __restrict__ up_prev,          // 2n x 64 bf16
    const bfr* __restrict__ wr, const float* __restrict__ b_r,
    const bfr* __restrict__ wh, const float* __restrict__ b_h,
    const bfr* __restrict__ wz, const float* __restrict__ b_z,
    bfr* __restrict__ up_cur,                 // n x 64 bf16
    float* __restrict__ out)                  // 4096 f32 or nullptr
{
    __shared__ bfr s_hhu[64][200];   // 192 cols + pad (row 400B: 16B-mult, %128B=16 -> 2-way max)
    __shared__ bfr s_t[64][200];
    __shared__ bfr s_hH[64][72];     // 64 cols + pad (row 144B)

    const int tid = threadIdx.x;
    const int lane = tid & 63, w = tid >> 6;
    const int ln = lane & 15, q = lane >> 4;
    const long r0 = (long)blockIdx.x * 64;

    // ---- stage h_L,h_R (cols 0..127) as 16B chunks ----
#pragma unroll
    for (int it = 0; it < 4; ++it) {
        int idx = tid + it * 256;             // 0..1023 = 64 rows x 16 chunks
        int row = idx >> 4, col0 = (idx & 15) * 8;
        const bfr* src = (col0 < 64)
            ? up_prev + (size_t)(2 * (r0 + row)) * H + col0
            : up_prev + (size_t)(2 * (r0 + row) + 1) * H + (col0 - 64);
        *(uint4*)&s_hhu[row][col0] = *(const uint4*)src;
    }
    // ---- compute u in-place (cols 128..191) ----
    {
        int r = tid & 63, c0 = (tid >> 6) * 16;
        float c[F];
        const float* cp = contents_lvl + (size_t)(r0 + r) * F;
#pragma unroll
        for (int k = 0; k < F; ++k) c[k] = cp[k];
#pragma unroll
        for (int cc = 0; cc < 16; ++cc) {
            int o = c0 + cc;
            const float* wu = W_u + o * F;
            float acc = b_u[o];
#pragma unroll
            for (int k = 0; k < F; ++k) acc += c[k] * wu[k];
            s_hhu[r][128 + o] = f2bfr(fmaxf(acc, 0.f));
        }
    }
    __syncthreads();

    const int mrow = w * 16 + ln;             // wave's A row for this lane

    // ---- mm1: R = hhu @ W_r^T ; t = sigmoid(R)*hhu ----
    {
        bf16x8 aF[6];
#pragma unroll
        for (int kt = 0; kt < 6; ++kt)
            aF[kt] = *(const bf16x8*)&s_hhu[mrow][kt * 32 + q * 8];
#pragma unroll
        for (int nt = 0; nt < 12; ++nt) {
            int ncol = nt * 16 + ln;
            f32x4 acc = {0.f, 0.f, 0.f, 0.f};
            const bfr* wp = wr + (size_t)ncol * 192 + q * 8;
#pragma unroll
            for (int kt = 0; kt < 6; ++kt)
                acc = __builtin_amdgcn_mfma_f32_16x16x32_bf16(
                    aF[kt], *(const bf16x8*)(wp + kt * 32), acc, 0, 0, 0);
            float bb = b_r[ncol];
            int rb = w * 16 + q * 4;
#pragma unroll
            for (int r = 0; r < 4; ++r) {
                float sg = 1.f / (1.f + __expf(-(acc[r] + bb)));
                s_t[rb + r][ncol] = f2bfr(sg * bfr2f(s_hhu[rb + r][ncol]));
            }
        }
    }
    __syncthreads();

    // ---- mm2: h_H = relu(t @ W_h^T) ----
    {
        bf16x8 aT[6];
#pragma unroll
        for (int kt = 0; kt < 6; ++kt)
            aT[kt] = *(const bf16x8*)&s_t[mrow][kt * 32 + q * 8];
#pragma unroll
        for (int nt = 0; nt < 4; ++nt) {
            int ncol = nt * 16 + ln;
            f32x4 acc = {0.f, 0.f, 0.f, 0.f};
            const bfr* wp = wh + (size_t)ncol * 192 + q * 8;
#pragma unroll
            for (int kt = 0; kt < 6; ++kt)
                acc = __builtin_amdgcn_mfma_f32_16x16x32_bf16(
                    aT[kt], *(const bf16x8*)(wp + kt * 32), acc, 0, 0, 0);
            float bb = b_h[ncol];
            int rb = w * 16 + q * 4;
#pragma unroll
            for (int r = 0; r < 4; ++r)
                s_hH[rb + r][ncol] = f2bfr(fmaxf(acc[r] + bb, 0.f));
        }
    }
    __syncthreads();

    // ---- mm3: z = [h_H, hhu] @ W_z^T ; softmax-4 gate ----
    {
        bf16x8 aZ[8];
        aZ[0] = *(const bf16x8*)&s_hH[mrow][q * 8];
        aZ[1] = *(const bf16x8*)&s_hH[mrow][32 + q * 8];
#pragma unroll
        for (int kt = 2; kt < 8; ++kt)
            aZ[kt] = *(const bf16x8*)&s_hhu[mrow][(kt - 2) * 32 + q * 8];

#pragma unroll
        for (int c = 0; c < 4; ++c) {
            f32x4 az[4];
#pragma unroll
            for (int g = 0; g < 4; ++g) {
                int n0 = g * 64 + c * 16;
                f32x4 acc = {0.f, 0.f, 0.f, 0.f};
                const bfr* wp = wz + (size_t)(n0 + ln) * 256 + q * 8;
#pragma unroll
                for (int kt = 0; kt < 8; ++kt)
                    acc = __builtin_amdgcn_mfma_f32_16x16x32_bf16(
                        aZ[kt], *(const bf16x8*)(wp + kt * 32), acc, 0, 0, 0);
                az[g] = acc;
            }
            int h = c * 16 + ln;
            float b0 = b_z[h], b1 = b_z[64 + h], b2 = b_z[128 + h], b3 = b_z[192 + h];
#pragma unroll
            for (int r = 0; r < 4; ++r) {
                int row = w * 16 + q * 4 + r;
                float z0 = az[0][r] + b0, z1 = az[1][r] + b1;
                float z2 = az[2][r] + b2, z3 = az[3][r] + b3;
                float m = fmaxf(fmaxf(z0, z1), fmaxf(z2, z3));
                float e0 = __expf(z0 - m), e1 = __expf(z1 - m);
                float e2 = __expf(z2 - m), e3 = __expf(z3 - m);
                float inv = 1.f / (e0 + e1 + e2 + e3);
                float v = (e0 * bfr2f(s_hH[row][h]) + e1 * bfr2f(s_hhu[row][h]) +
                           e2 * bfr2f(s_hhu[row][64 + h]) + e3 * bfr2f(s_hhu[row][128 + h])) * inv;
                size_t gidx = (size_t)(r0 + row) * H + h;
                up_cur[gidx] = f2bfr(v);
                if (out) out[gidx] = v;
            }
        }
    }
}

extern "C" void kernel_launch(void* const* d_in, const int* in_sizes, int n_in,
                              void* d_out, int out_size, void* d_ws, size_t ws_size,
                              hipStream_t stream) {
    const float* contents = (const float*)d_in[0];
    const float* W_u = (const float*)d_in[1];
    const float* b_u = (const float*)d_in[2];
    const float* W_r = (const float*)d_in[3];
    const float* b_r = (const float*)d_in[4];
    const float* W_h = (const float*)d_in[5];
    const float* b_h = (const float*)d_in[6];
    const float* W_z = (const float*)d_in[7];
    const float* b_z = (const float*)d_in[8];
    float* out = (float*)d_out;

    int SIZES[13], OFFS[14];
    OFFS[0] = 0;
    for (int j = 0; j < 13; ++j) { SIZES[j] = 64 << j; OFFS[j + 1] = OFFS[j] + SIZES[j]; }

    // ws layout (bf16 bits): u12 | buf_odd | buf_even | wr | wh | wz
    bfr* u12 = (bfr*)d_ws;                                  // 262144*64
    bfr* buf_odd = u12 + (size_t)262144 * H;                // 131072*64
    bfr* buf_even = buf_odd + (size_t)131072 * H;           // 65536*64
    bfr* wr = buf_even + (size_t)65536 * H;                 // 36864
    bfr* wh = wr + 36864;                                   // 12288
    bfr* wz = wh + 12288;                                   // 65536

    convert_weights<<<256, 256, 0, stream>>>(W_r, W_h, W_z, wr, wh, wz);
    int totalU = 262144 * H;
    u12_kernel<<<totalU / 256, 256, 0, stream>>>(contents + (size_t)OFFS[12] * F, W_u, b_u, u12, totalU);

    const bfr* up_prev = u12;
    for (int j = 11; j >= 0; --j) {
        int n = SIZES[j];
        bfr* up_cur = (j & 1) ? buf_odd : buf_even;
        level_kernel<<<n / 64, 256, 0, stream>>>(
            contents + (size_t)OFFS[j] * F, W_u, b_u, up_prev,
            wr, b_r, wh, b_h, wz, b_z,
            up_cur, (j == 0) ? out : nullptr);
        up_prev = up_cur;
    }
}

// Round 4
// 342.947 us; speedup vs baseline: 7.4235x; 2.1952x over previous
//
#include <hip/hip_runtime.h>
#include <hip/hip_bf16.h>

// GRNNTransformGated, round 3: N-split MFMA.
// Block = 256 thr (4 waves) x 64 rows. Each wave owns an N-SLICE of each
// matmul and computes all 4 M-tiles -> every weight fragment read once per
// BLOCK (round 2 read it once per WAVE: 4x the L2 traffic), and each B-frag
// feeds 4-16 MFMAs instead of 1.
// Weights are pre-packed into MFMA B-fragment order (convert_weights), so a
// wave's B-load is one contiguous 1KB chunk (coalesced dwordx4/lane).
// Activations (hhu, t, hH) live in LDS in A-fragment order: ds_read_b128
// conflict-free, no padding. LDS = 57.3KB -> 2 blocks/CU.
// mm1: hhu@W_r^T (N=192,K=192) -> t = sigmoid*hhu   (wave: 3 n-tiles)
// mm2: t@W_h^T   (N=64, K=192) -> h_H = relu        (wave: 1 n-tile)
// mm3: [h_H,hhu]@W_z^T (N=256,K=256), groups {h,64+h,128+h,192+h} per wave
//      -> softmax-4 gate in registers.

#define H 64
#define F 7

typedef __bf16 bf16x8 __attribute__((ext_vector_type(8)));
typedef float f32x4 __attribute__((ext_vector_type(4)));
typedef unsigned short bfr;   // raw bf16 bits

__device__ __forceinline__ float bfr2f(bfr v) { return __uint_as_float(((unsigned)v) << 16); }
__device__ __forceinline__ bfr f2bfr(float f) {
    __hip_bfloat16 h = __float2bfloat16(f);
    return __builtin_bit_cast(bfr, h);
}

// fragment-order address: elements, lane (ln,q) frag (Mt,kt) starts at fidx(...)
__device__ __forceinline__ int fidx(int Mt, int kt, int q, int ln, int KT) {
    return ((((Mt * KT + kt) * 4 + q) * 16 + ln) * 8);
}
__device__ __forceinline__ int fidx_rk(int row, int k, int KT) {
    return fidx(row >> 4, k >> 5, (k >> 3) & 3, row & 15, KT) + (k & 7);
}

// pack weight matrix (N x K, f32 row-major) into B-fragment order bf16:
// dest[(((ntile*KT + kt)*4 + q)*16 + lnc)*8 + j] = W[(ntile*16+lnc)*K + kt*32+q*8+j]
__device__ __forceinline__ void pack_one(const float* __restrict__ W, bfr* __restrict__ dst,
                                         int d, int K) {
    int KT = K >> 5;
    int j = d & 7, lnc = (d >> 3) & 15, q = (d >> 7) & 3;
    int t1 = d >> 9;
    int kt = t1 % KT, ntile = t1 / KT;
    int ncol = ntile * 16 + lnc;
    int k = kt * 32 + q * 8 + j;
    dst[d] = f2bfr(W[(size_t)ncol * K + k]);
}

__global__ void convert_weights(const float* __restrict__ Wr, const float* __restrict__ Wh,
                                const float* __restrict__ Wz,
                                bfr* __restrict__ wr, bfr* __restrict__ wh, bfr* __restrict__ wz) {
    int i = blockIdx.x * 256 + threadIdx.x;   // grid covers 65536
    if (i < 36864) pack_one(Wr, wr, i, 192);
    if (i < 12288) pack_one(Wh, wh, i, 192);
    if (i < 65536) pack_one(Wz, wz, i, 256);
}

__global__ void u12_kernel(const float* __restrict__ contents12,
                           const float* __restrict__ W_u, const float* __restrict__ b_u,
                           bfr* __restrict__ u12, int total) {
    int idx = blockIdx.x * blockDim.x + threadIdx.x;
    if (idx >= total) return;
    int row = idx >> 6, h = idx & 63;
    const float* c = contents12 + (size_t)row * F;
    const float* w = W_u + (size_t)h * F;
    float acc = b_u[h];
#pragma unroll
    for (int k = 0; k < F; ++k) acc += c[k] * w[k];
    u12[idx] = f2bfr(fmaxf(acc, 0.f));
}

__global__ __launch_bounds__(256, 2) void level_kernel(
    const float* __restrict__ contents_lvl,   // level rows x 7 (f32)
    const float* __restrict__ W_u, const float* __restrict__ b_u,
    const bfr* __restrict__ up_prev,          // 2n x 64 bf16 row-major
    const bfr* __restrict__ wr, const float* __restrict__ b_r,
    const bfr* __restrict__ wh, const float* __restrict__ b_h,
    const bfr* __restrict__ wz, const float* __restrict__ b_z,
    bfr* __restrict__ up_cur,                 // n x 64 bf16 row-major
    float* __restrict__ out)                  // 4096 f32 or nullptr
{
    __shared__ bfr s_hhu[12288];  // 64 rows x K=192, fragment order (KT=6)
    __shared__ bfr s_t[12288];    // same
    __shared__ bfr s_hH[4096];    // 64 rows x K=64,  fragment order (KT=2)

    const int tid = threadIdx.x;
    const int lane = tid & 63, w = tid >> 6;
    const int ln = lane & 15, q = lane >> 4;
    const size_t r0 = (size_t)blockIdx.x * 64;

    // ---- stage h_L,h_R (k=0..127 -> kt=0..3) in fragment order, 16B chunks ----
#pragma unroll
    for (int it = 0; it < 4; ++it) {
        int idx = it * 256 + tid;             // 1024 chunks
        int lns = idx & 15, qs = (idx >> 4) & 3, kts = (idx >> 6) & 3, Mts = idx >> 8;
        int row = Mts * 16 + lns, k = kts * 32 + qs * 8;
        const bfr* src = (k < 64)
            ? up_prev + (size_t)(2 * (r0 + row)) * H + k
            : up_prev + (size_t)(2 * (r0 + row) + 1) * H + (k - 64);
        *(uint4*)&s_hhu[fidx(Mts, kts, qs, lns, 6)] = *(const uint4*)src;
    }
    // ---- compute u in-place (k=128..191 -> kt=4..5) ----
#pragma unroll
    for (int it = 0; it < 2; ++it) {
        int idx = it * 256 + tid;             // 512 chunks of 8 outputs
        int lns = idx & 15, qs = (idx >> 4) & 3, ktl = (idx >> 6) & 1, Mts = (idx >> 7) & 3;
        int row = Mts * 16 + lns, o0 = ktl * 32 + qs * 8;
        float c[F];
        const float* cp = contents_lvl + (size_t)(r0 + row) * F;
#pragma unroll
        for (int k = 0; k < F; ++k) c[k] = cp[k];
        bfr tmp[8];
#pragma unroll
        for (int j = 0; j < 8; ++j) {
            int o = o0 + j;
            const float* wu = W_u + o * F;
            float acc = b_u[o];
#pragma unroll
            for (int k = 0; k < F; ++k) acc += c[k] * wu[k];
            tmp[j] = f2bfr(fmaxf(acc, 0.f));
        }
        *(uint4*)&s_hhu[fidx(Mts, 4 + ktl, qs, lns, 6)] = *(const uint4*)tmp;
    }
    __syncthreads();

    // ---- mm1: t = sigmoid(hhu @ W_r^T + b_r) * hhu ; wave w: n-tiles 3w..3w+2 ----
    {
        bf16x8 A1[4][6];
#pragma unroll
        for (int Mt = 0; Mt < 4; ++Mt)
#pragma unroll
            for (int kt = 0; kt < 6; ++kt)
                A1[Mt][kt] = *(const bf16x8*)&s_hhu[fidx(Mt, kt, q, ln, 6)];
#pragma unroll
        for (int nt = 0; nt < 3; ++nt) {
            int ntile = w * 3 + nt;
            int ncol = ntile * 16 + ln;
            bf16x8 Bf[6];
#pragma unroll
            for (int kt = 0; kt < 6; ++kt)
                Bf[kt] = *(const bf16x8*)&wr[fidx(ntile, kt, q, ln, 6)];
            float bb = b_r[ncol];
#pragma unroll
            for (int Mt = 0; Mt < 4; ++Mt) {
                f32x4 acc = {0.f, 0.f, 0.f, 0.f};
#pragma unroll
                for (int kt = 0; kt < 6; ++kt)
                    acc = __builtin_amdgcn_mfma_f32_16x16x32_bf16(A1[Mt][kt], Bf[kt], acc, 0, 0, 0);
#pragma unroll
                for (int r = 0; r < 4; ++r) {
                    int row = Mt * 16 + q * 4 + r;
                    float sg = 1.f / (1.f + __expf(-(acc[r] + bb)));
                    s_t[fidx_rk(row, ncol, 6)] =
                        f2bfr(sg * bfr2f(s_hhu[fidx_rk(row, ncol, 6)]));
                }
            }
        }
    }
    __syncthreads();

    // ---- mm2: h_H = relu(t @ W_h^T + b_h) ; wave w: n-tile w ----
    {
        int ncol = w * 16 + ln;
        bf16x8 Bf[6];
#pragma unroll
        for (int kt = 0; kt < 6; ++kt)
            Bf[kt] = *(const bf16x8*)&wh[fidx(w, kt, q, ln, 6)];
        float bb = b_h[ncol];
#pragma unroll
        for (int Mt = 0; Mt < 4; ++Mt) {
            f32x4 acc = {0.f, 0.f, 0.f, 0.f};
#pragma unroll
            for (int kt = 0; kt < 6; ++kt) {
                bf16x8 a = *(const bf16x8*)&s_t[fidx(Mt, kt, q, ln, 6)];
                acc = __builtin_amdgcn_mfma_f32_16x16x32_bf16(a, Bf[kt], acc, 0, 0, 0);
            }
#pragma unroll
            for (int r = 0; r < 4; ++r) {
                int row = Mt * 16 + q * 4 + r;
                s_hH[fidx_rk(row, ncol, 2)] = f2bfr(fmaxf(acc[r] + bb, 0.f));
            }
        }
    }
    __syncthreads();

    // ---- mm3: z = [h_H,hhu] @ W_z^T + b_z ; wave w: cols {g*64 + w*16+ln} ----
    {
        int hcol = w * 16 + ln;
        bf16x8 Bz[4][8];
#pragma unroll
        for (int g = 0; g < 4; ++g) {
            int ntile = g * 4 + w;
#pragma unroll
            for (int kt = 0; kt < 8; ++kt)
                Bz[g][kt] = *(const bf16x8*)&wz[fidx(ntile, kt, q, ln, 8)];
        }
        float b0 = b_z[hcol], b1 = b_z[64 + hcol], b2 = b_z[128 + hcol], b3 = b_z[192 + hcol];
#pragma unroll
        for (int Mt = 0; Mt < 4; ++Mt) {
            bf16x8 Az[8];
            Az[0] = *(const bf16x8*)&s_hH[fidx(Mt, 0, q, ln, 2)];
            Az[1] = *(const bf16x8*)&s_hH[fidx(Mt, 1, q, ln, 2)];
#pragma unroll
            for (int kt = 0; kt < 6; ++kt)
                Az[2 + kt] = *(const bf16x8*)&s_hhu[fidx(Mt, kt, q, ln, 6)];
            f32x4 az[4];
#pragma unroll
            for (int g = 0; g < 4; ++g) {
                f32x4 acc = {0.f, 0.f, 0.f, 0.f};
#pragma unroll
                for (int kt = 0; kt < 8; ++kt)
                    acc = __builtin_amdgcn_mfma_f32_16x16x32_bf16(Az[kt], Bz[g][kt], acc, 0, 0, 0);
                az[g] = acc;
            }
#pragma unroll
            for (int r = 0; r < 4; ++r) {
                int row = Mt * 16 + q * 4 + r;
                float z0 = az[0][r] + b0, z1 = az[1][r] + b1;
                float z2 = az[2][r] + b2, z3 = az[3][r] + b3;
                float m = fmaxf(fmaxf(z0, z1), fmaxf(z2, z3));
                float e0 = __expf(z0 - m), e1 = __expf(z1 - m);
                float e2 = __expf(z2 - m), e3 = __expf(z3 - m);
                float inv = 1.f / (e0 + e1 + e2 + e3);
                float v = (e0 * bfr2f(s_hH[fidx_rk(row, hcol, 2)]) +
                           e1 * bfr2f(s_hhu[fidx_rk(row, hcol, 6)]) +
                           e2 * bfr2f(s_hhu[fidx_rk(row, 64 + hcol, 6)]) +
                           e3 * bfr2f(s_hhu[fidx_rk(row, 128 + hcol, 6)])) * inv;
                size_t gidx = (size_t)(r0 + row) * H + hcol;
                up_cur[gidx] = f2bfr(v);
                if (out) out[gidx] = v;
            }
        }
    }
}

extern "C" void kernel_launch(void* const* d_in, const int* in_sizes, int n_in,
                              void* d_out, int out_size, void* d_ws, size_t ws_size,
                              hipStream_t stream) {
    const float* contents = (const float*)d_in[0];
    const float* W_u = (const float*)d_in[1];
    const float* b_u = (const float*)d_in[2];
    const float* W_r = (const float*)d_in[3];
    const float* b_r = (const float*)d_in[4];
    const float* W_h = (const float*)d_in[5];
    const float* b_h = (const float*)d_in[6];
    const float* W_z = (const float*)d_in[7];
    const float* b_z = (const float*)d_in[8];
    float* out = (float*)d_out;

    int SIZES[13], OFFS[14];
    OFFS[0] = 0;
    for (int j = 0; j < 13; ++j) { SIZES[j] = 64 << j; OFFS[j + 1] = OFFS[j] + SIZES[j]; }

    // ws layout (bf16 bits): u12 | buf_odd | buf_even | wr | wh | wz
    bfr* u12 = (bfr*)d_ws;                                  // 262144*64
    bfr* buf_odd = u12 + (size_t)262144 * H;                // 131072*64
    bfr* buf_even = buf_odd + (size_t)131072 * H;           // 65536*64
    bfr* wr = buf_even + (size_t)65536 * H;                 // 36864
    bfr* wh = wr + 36864;                                   // 12288
    bfr* wz = wh + 12288;                                   // 65536

    convert_weights<<<256, 256, 0, stream>>>(W_r, W_h, W_z, wr, wh, wz);
    int totalU = 262144 * H;
    u12_kernel<<<totalU / 256, 256, 0, stream>>>(contents + (size_t)OFFS[12] * F, W_u, b_u, u12, totalU);

    const bfr* up_prev = u12;
    for (int j = 11; j >= 0; --j) {
        int n = SIZES[j];
        bfr* up_cur = (j & 1) ? buf_odd : buf_even;
        level_kernel<<<n / 64, 256, 0, stream>>>(
            contents + (size_t)OFFS[j] * F, W_u, b_u, up_prev,
            wr, b_r, wh, b_h, wz, b_z,
            up_cur, (j == 0) ? out : nullptr);
        up_prev = up_cur;
    }
}